// Round 8
// baseline (214.951 us; speedup 1.0000x reference)
//
#include <hip/hip_runtime.h>
#include <math.h>

#define N_NODES 50000
#define D       64
#define N_EDGES 800000
#define N_HEAD  4

typedef unsigned short ushort_t;
typedef unsigned int   uint_t;
typedef float f32x4 __attribute__((ext_vector_type(4)));
typedef unsigned int u32x2 __attribute__((ext_vector_type(2)));

// bf16 <-> fp32 bit helpers (RNE on pack)
__device__ __forceinline__ float bf_lo(uint_t u) {
    return __uint_as_float(u << 16);
}
__device__ __forceinline__ float bf_hi(uint_t u) {
    return __uint_as_float(u & 0xffff0000u);
}
__device__ __forceinline__ ushort_t f2bf(float f) {
    uint_t u = __float_as_uint(f);
    u += 0x7fffu + ((u >> 16) & 1u);   // round-to-nearest-even
    return (ushort_t)(u >> 16);
}

// ---------------------------------------------------------------------------
// prep: cv[e] = (col<<16) | bf16(val);  row_ptr via binary search (sorted rows)
// ---------------------------------------------------------------------------
__global__ void prep_kernel(const int* __restrict__ edge_row,
                            const int* __restrict__ edge_col,
                            const float* __restrict__ edge_val,
                            int* __restrict__ row_ptr,
                            uint_t* __restrict__ cv) {
    const int i = blockIdx.x * blockDim.x + threadIdx.x;
    if (i < N_EDGES)
        __builtin_nontemporal_store(
            ((uint_t)edge_col[i] << 16) | (uint_t)f2bf(edge_val[i]), cv + i);
    if (i <= N_NODES) {
        int lo = 0, hi = N_EDGES;
        while (lo < hi) {
            int mid = (lo + hi) >> 1;
            if (edge_row[mid] < i) lo = mid + 1; else hi = mid;
        }
        row_ptr[i] = lo;
    }
}

// ---------------------------------------------------------------------------
// t[n][j] = bf16( elu( sum_k in[n][k] * W[j][k] + b[j] ) )
// lane j holds W[j][*] in 64 VGPRs; row data via wave-uniform scalar loads.
// BF16IN=0: fp32 input + event_type mask (head 0). BF16IN=1: bf16 h input.
// ---------------------------------------------------------------------------
template<int BF16IN>
__global__ __launch_bounds__(256) void linear_elu_kernel(
        const void* __restrict__ in,
        const float* __restrict__ W,   // [64][64] row-major, W[j][k]
        const float* __restrict__ b,   // [64]
        const int*  __restrict__ et,   // mask if et[n]==0 (BF16IN=0 only)
        ushort_t* __restrict__ t) {
    const int lane = threadIdx.x & 63;
    const int wid  = (blockIdx.x * blockDim.x + threadIdx.x) >> 6;
    const int nwav = (gridDim.x * blockDim.x) >> 6;

    float4 w4[16];
    {
        const float4* wp = (const float4*)(W + lane * D);
        #pragma unroll
        for (int i = 0; i < 16; ++i) w4[i] = wp[i];
    }
    const float* w = (const float*)w4;
    const float bj = b[lane];

    for (int row0 = wid; row0 < N_NODES; row0 += nwav) {
        const int row = __builtin_amdgcn_readfirstlane(row0);
        float acc = bj;
        if (BF16IN) {
            const uint_t* rp = (const uint_t*)in + (size_t)row * 32;
            #pragma unroll
            for (int k2 = 0; k2 < 32; ++k2) {
                const uint_t u = rp[k2];
                acc = fmaf(bf_lo(u), w[2 * k2 + 0], acc);
                acc = fmaf(bf_hi(u), w[2 * k2 + 1], acc);
            }
        } else {
            if (et[row] != 0) {
                const float* rp = (const float*)in + (size_t)row * D;
                #pragma unroll
                for (int k = 0; k < D; ++k)
                    acc = fmaf(rp[k], w[k], acc);
            }
        }
        const float e = (acc > 0.f) ? acc : expm1f(acc);
        __builtin_nontemporal_store(f2bf(e), t + (size_t)row * D + lane);
    }
}

// ---------------------------------------------------------------------------
// SpMM: h[r][:] = sum_{e in row r} val[e] * t[col[e]][:]   (t bf16, cv packed)
// TWO rows per wave (r and r+N/2), chunk-A (16 edges) metadata + gathers for
// BOTH rows issued before any consumption -> up to 64 cache lines in flight
// per wave. deg>16 remainder handled per-row, wave-uniform (no dummy traffic).
// All streaming accesses (cv, out, h) are nontemporal so per-XCD L2 stays
// dedicated to the gathered t table.
// ---------------------------------------------------------------------------
__global__ __launch_bounds__(256) void spmm_kernel(
        const ushort_t* __restrict__ tin,   // bf16 [N][64]
        const uint_t* __restrict__ cv,      // (col<<16)|bf16(val) [E]
        const int*   __restrict__ row_ptr,
        ushort_t* __restrict__ h,           // bf16 [N][64] (if write_h)
        float* __restrict__ out,
        int first_head, int write_h) {
    const int lane = threadIdx.x & 63;
    const int g    = lane >> 4;    // edge slot within quad
    const int l    = lane & 15;    // dim quad: dims [4l, 4l+4)
    const int wid  = (blockIdx.x * blockDim.x + threadIdx.x) >> 6;
    if (wid >= N_NODES / 2) return;
    const int rA = __builtin_amdgcn_readfirstlane(wid);
    const int rB = rA + N_NODES / 2;

    // ---- metadata round: both rows' bounds + chunk-A cv, all in flight ----
    const int e0a = row_ptr[rA], e1a = row_ptr[rA + 1];
    const int e0b = row_ptr[rB], e1b = row_ptr[rB + 1];
    const int cla = (e1a > 0) ? e1a - 1 : 0;
    const int clb = (e1b > 0) ? e1b - 1 : 0;

    int   ca[4], cb[4];
    float va[4], vb[4];
    #pragma unroll
    for (int u = 0; u < 4; ++u) {
        const int  ce = e0a + 4 * u + g;
        const bool ok = ce < e1a;
        const uint_t p = __builtin_nontemporal_load(cv + (ok ? ce : cla));
        ca[u] = (int)(p >> 16);
        va[u] = ok ? bf_lo(p) : 0.f;
    }
    #pragma unroll
    for (int u = 0; u < 4; ++u) {
        const int  ce = e0b + 4 * u + g;
        const bool ok = ce < e1b;
        const uint_t p = __builtin_nontemporal_load(cv + (ok ? ce : clb));
        cb[u] = (int)(p >> 16);
        vb[u] = ok ? bf_lo(p) : 0.f;
    }

    // ---- gather round: 8 dwordx2 gathers (64 lines) in flight ----
    uint2 ra[4], rb[4];
    #pragma unroll
    for (int u = 0; u < 4; ++u)
        ra[u] = *(const uint2*)(tin + (size_t)ca[u] * D + l * 4);
    #pragma unroll
    for (int u = 0; u < 4; ++u)
        rb[u] = *(const uint2*)(tin + (size_t)cb[u] * D + l * 4);

    float4 accA = {0.f, 0.f, 0.f, 0.f};
    float4 accB = {0.f, 0.f, 0.f, 0.f};
    #pragma unroll
    for (int u = 0; u < 4; ++u) {
        accA.x = fmaf(va[u], bf_lo(ra[u].x), accA.x);
        accA.y = fmaf(va[u], bf_hi(ra[u].x), accA.y);
        accA.z = fmaf(va[u], bf_lo(ra[u].y), accA.z);
        accA.w = fmaf(va[u], bf_hi(ra[u].y), accA.w);
    }
    #pragma unroll
    for (int u = 0; u < 4; ++u) {
        accB.x = fmaf(vb[u], bf_lo(rb[u].x), accB.x);
        accB.y = fmaf(vb[u], bf_hi(rb[u].x), accB.y);
        accB.z = fmaf(vb[u], bf_lo(rb[u].y), accB.z);
        accB.w = fmaf(vb[u], bf_hi(rb[u].y), accB.w);
    }

    // ---- per-row remainder (deg > 16), wave-uniform, masked 16-edge chunks
    for (int e = e0a + 16; e < e1a; e += 16) {
        int   c[4]; float v[4]; uint2 r[4];
        #pragma unroll
        for (int u = 0; u < 4; ++u) {
            const int  ce = e + 4 * u + g;
            const bool ok = ce < e1a;
            const uint_t p = __builtin_nontemporal_load(cv + (ok ? ce : cla));
            c[u] = (int)(p >> 16);
            v[u] = ok ? bf_lo(p) : 0.f;
        }
        #pragma unroll
        for (int u = 0; u < 4; ++u)
            r[u] = *(const uint2*)(tin + (size_t)c[u] * D + l * 4);
        #pragma unroll
        for (int u = 0; u < 4; ++u) {
            accA.x = fmaf(v[u], bf_lo(r[u].x), accA.x);
            accA.y = fmaf(v[u], bf_hi(r[u].x), accA.y);
            accA.z = fmaf(v[u], bf_lo(r[u].y), accA.z);
            accA.w = fmaf(v[u], bf_hi(r[u].y), accA.w);
        }
    }
    for (int e = e0b + 16; e < e1b; e += 16) {
        int   c[4]; float v[4]; uint2 r[4];
        #pragma unroll
        for (int u = 0; u < 4; ++u) {
            const int  ce = e + 4 * u + g;
            const bool ok = ce < e1b;
            const uint_t p = __builtin_nontemporal_load(cv + (ok ? ce : clb));
            c[u] = (int)(p >> 16);
            v[u] = ok ? bf_lo(p) : 0.f;
        }
        #pragma unroll
        for (int u = 0; u < 4; ++u)
            r[u] = *(const uint2*)(tin + (size_t)c[u] * D + l * 4);
        #pragma unroll
        for (int u = 0; u < 4; ++u) {
            accB.x = fmaf(v[u], bf_lo(r[u].x), accB.x);
            accB.y = fmaf(v[u], bf_hi(r[u].x), accB.y);
            accB.z = fmaf(v[u], bf_lo(r[u].y), accB.z);
            accB.w = fmaf(v[u], bf_hi(r[u].y), accB.w);
        }
    }

    // ---- reduce across the 4 groups (lane bits 4,5) ----
    #pragma unroll
    for (int off = 16; off < 64; off <<= 1) {
        accA.x += __shfl_xor(accA.x, off, 64);
        accA.y += __shfl_xor(accA.y, off, 64);
        accA.z += __shfl_xor(accA.z, off, 64);
        accA.w += __shfl_xor(accA.w, off, 64);
        accB.x += __shfl_xor(accB.x, off, 64);
        accB.y += __shfl_xor(accB.y, off, 64);
        accB.z += __shfl_xor(accB.z, off, 64);
        accB.w += __shfl_xor(accB.w, off, 64);
    }

    if (g == 0) {
        const size_t baseA = (size_t)rA * D + (size_t)l * 4;
        const size_t baseB = (size_t)rB * D + (size_t)l * 4;
        f32x4 oa = {accA.x, accA.y, accA.z, accA.w};
        f32x4 ob = {accB.x, accB.y, accB.z, accB.w};
        if (!first_head) {
            oa += __builtin_nontemporal_load((const f32x4*)(out + baseA));
            ob += __builtin_nontemporal_load((const f32x4*)(out + baseB));
        }
        __builtin_nontemporal_store(oa, (f32x4*)(out + baseA));
        __builtin_nontemporal_store(ob, (f32x4*)(out + baseB));
        if (write_h) {
            u32x2 ha, hb;
            ha.x = (uint_t)f2bf(accA.x) | ((uint_t)f2bf(accA.y) << 16);
            ha.y = (uint_t)f2bf(accA.z) | ((uint_t)f2bf(accA.w) << 16);
            hb.x = (uint_t)f2bf(accB.x) | ((uint_t)f2bf(accB.y) << 16);
            hb.y = (uint_t)f2bf(accB.z) | ((uint_t)f2bf(accB.w) << 16);
            __builtin_nontemporal_store(ha, (u32x2*)(h + baseA));
            __builtin_nontemporal_store(hb, (u32x2*)(h + baseB));
        }
    }
}

// ---------------------------------------------------------------------------
extern "C" void kernel_launch(void* const* d_in, const int* in_sizes, int n_in,
                              void* d_out, int out_size, void* d_ws, size_t ws_size,
                              hipStream_t stream) {
    const float* x        = (const float*)d_in[0];  // [N, 64]
    const float* edge_val = (const float*)d_in[1];  // [E]
    const float* W        = (const float*)d_in[2];  // [4, 64, 64]
    const float* b        = (const float*)d_in[3];  // [4, 64]
    const int* edge_row   = (const int*)d_in[4];    // sorted
    const int* edge_col   = (const int*)d_in[5];
    const int* event_type = (const int*)d_in[6];    // [N] (int32 on device)
    float* out = (float*)d_out;

    // ws: cv uint32[E] | row_ptr[N+2] | t bf16[N*64] | h bf16[N*64]
    char* p = (char*)d_ws;
    uint_t*   cv      = (uint_t*)p;                  p += (size_t)N_EDGES * 4;
    int*      row_ptr = (int*)p;                     p += (size_t)(N_NODES + 2) * 4;
    p = (char*)(((uintptr_t)p + 15) & ~(uintptr_t)15);
    ushort_t* t       = (ushort_t*)p;                p += (size_t)N_NODES * D * 2;
    ushort_t* h       = (ushort_t*)p;

    prep_kernel<<<(N_EDGES + 255) / 256, 256, 0, stream>>>(
        edge_row, edge_col, edge_val, row_ptr, cv);

    const int sblk = (N_NODES / 2 * 64 + 255) / 256;  // 2 rows per wave

    // head 0: linear(x fp32, masked) -> t ; spmm(t) -> h, out =
    linear_elu_kernel<0><<<1024, 256, 0, stream>>>(x, W, b, event_type, t);
    spmm_kernel<<<sblk, 256, 0, stream>>>(t, cv, row_ptr, h, out, 1, 1);

    // heads 1..3: linear(h bf16) -> t ; spmm(t) -> h, out +=
    for (int i = 1; i < N_HEAD; ++i) {
        linear_elu_kernel<1><<<1024, 256, 0, stream>>>(
            h, W + (size_t)i * D * D, b + (size_t)i * D, nullptr, t);
        spmm_kernel<<<sblk, 256, 0, stream>>>(
            t, cv, row_ptr, h, out, 0, (i < N_HEAD - 1) ? 1 : 0);
    }
}

// Round 9
// 201.861 us; speedup vs baseline: 1.0648x; 1.0648x over previous
//
#include <hip/hip_runtime.h>
#include <math.h>

#define N_NODES 50000
#define D       64
#define N_EDGES 800000
#define N_HEAD  4
#define ELLW    32     // ELL width: P(deg>32 | Poisson(16)) ~ 1e-4, CSR fallback

typedef unsigned short ushort_t;
typedef unsigned int   uint_t;
typedef float f32x4 __attribute__((ext_vector_type(4)));

// bf16 <-> fp32 bit helpers (RNE on pack)
__device__ __forceinline__ float bf_lo(uint_t u) {
    return __uint_as_float(u << 16);
}
__device__ __forceinline__ float bf_hi(uint_t u) {
    return __uint_as_float(u & 0xffff0000u);
}
__device__ __forceinline__ ushort_t f2bf(float f) {
    uint_t u = __float_as_uint(f);
    u += 0x7fffu + ((u >> 16) & 1u);   // round-to-nearest-even
    return (ushort_t)(u >> 16);
}

// ---------------------------------------------------------------------------
// prep1: row_ptr[r] = lower_bound(edge_row, r)  (edge_row sorted)
// ---------------------------------------------------------------------------
__global__ void prep1_kernel(const int* __restrict__ edge_row,
                             int* __restrict__ row_ptr) {
    const int i = blockIdx.x * blockDim.x + threadIdx.x;
    if (i > N_NODES) return;
    int lo = 0, hi = N_EDGES;
    while (lo < hi) {
        int mid = (lo + hi) >> 1;
        if (edge_row[mid] < i) lo = mid + 1; else hi = mid;
    }
    row_ptr[i] = lo;
}

// ---------------------------------------------------------------------------
// prep2: ELL build. epad[row][slot] = (col<<16)|bf16(val) for slot<deg, else 0.
// One thread per (row,slot); consecutive threads read consecutive edges.
// ---------------------------------------------------------------------------
__global__ void prep2_kernel(const int* __restrict__ edge_col,
                             const float* __restrict__ edge_val,
                             const int* __restrict__ row_ptr,
                             uint_t* __restrict__ epad,
                             int* __restrict__ degarr) {
    const int i = blockIdx.x * blockDim.x + threadIdx.x;
    if (i >= N_NODES * ELLW) return;
    const int row  = i >> 5;
    const int slot = i & (ELLW - 1);
    const int e0 = row_ptr[row];
    const int deg = row_ptr[row + 1] - e0;
    uint_t v = 0u;
    if (slot < deg && slot < ELLW) {
        const int e = e0 + slot;
        v = ((uint_t)edge_col[e] << 16) | (uint_t)f2bf(edge_val[e]);
    }
    epad[i] = v;
    if (slot == 0) degarr[row] = deg;
}

// ---------------------------------------------------------------------------
// t[n][j] = bf16( elu( sum_k in[n][k] * W[j][k] + b[j] ) )
// lane j holds W[j][*] in 64 VGPRs; row data via wave-uniform scalar loads.
// BF16IN=0: fp32 input + event_type mask (head 0). BF16IN=1: bf16 h input.
// ---------------------------------------------------------------------------
template<int BF16IN>
__global__ __launch_bounds__(256) void linear_elu_kernel(
        const void* __restrict__ in,
        const float* __restrict__ W,   // [64][64] row-major, W[j][k]
        const float* __restrict__ b,   // [64]
        const int*  __restrict__ et,   // mask if et[n]==0 (BF16IN=0 only)
        ushort_t* __restrict__ t) {
    const int lane = threadIdx.x & 63;
    const int wid  = (blockIdx.x * blockDim.x + threadIdx.x) >> 6;
    const int nwav = (gridDim.x * blockDim.x) >> 6;

    float4 w4[16];
    {
        const float4* wp = (const float4*)(W + lane * D);
        #pragma unroll
        for (int i = 0; i < 16; ++i) w4[i] = wp[i];
    }
    const float* w = (const float*)w4;
    const float bj = b[lane];

    for (int row0 = wid; row0 < N_NODES; row0 += nwav) {
        const int row = __builtin_amdgcn_readfirstlane(row0);
        float acc = bj;
        if (BF16IN) {
            const uint_t* rp = (const uint_t*)in + (size_t)row * 32;
            #pragma unroll
            for (int k2 = 0; k2 < 32; ++k2) {
                const uint_t u = rp[k2];
                acc = fmaf(bf_lo(u), w[2 * k2 + 0], acc);
                acc = fmaf(bf_hi(u), w[2 * k2 + 1], acc);
            }
        } else {
            if (et[row] != 0) {
                const float* rp = (const float*)in + (size_t)row * D;
                #pragma unroll
                for (int k = 0; k < D; ++k)
                    acc = fmaf(rp[k], w[k], acc);
            }
        }
        const float e = (acc > 0.f) ? acc : expm1f(acc);
        t[(size_t)row * D + lane] = f2bf(e);
    }
}

// ---------------------------------------------------------------------------
// SpMM via ELL: h[r][:] = sum_s epad.val[r][s] * t[epad.col[r][s]][:]
// One wave per row; 4 groups of 16 lanes; group g owns slots 4g..4g+3 (A)
// and 16+4g..16+4g+3 (B), loaded as TWO dwordx4 (addresses depend only on
// row -> issue immediately; no row_ptr on the critical path). degarr and the
// out-RMW load issue in the same round. Round 2 = up to 8 exec-masked
// gathers (v==0 dummy slots generate NO memory traffic; exact skip).
// 2 dependent memory rounds per row vs 3 in the CSR version.
// deg>32 overflow (~1e-4 of rows) falls back to CSR, wave-uniform.
// ---------------------------------------------------------------------------
__global__ __launch_bounds__(256) void spmm_kernel(
        const ushort_t* __restrict__ tin,   // bf16 [N][64]
        const uint_t* __restrict__ epad,    // ELL [N][32]
        const int*   __restrict__ degarr,   // [N]
        const int*   __restrict__ row_ptr,  // [N+1] (overflow path only)
        const int*   __restrict__ edge_col, // (overflow path only)
        const float* __restrict__ edge_val, // (overflow path only)
        ushort_t* __restrict__ h,           // bf16 [N][64] (if write_h)
        float* __restrict__ out,
        int first_head, int write_h) {
    const int lane = threadIdx.x & 63;
    const int g    = lane >> 4;    // slot quad within row
    const int l    = lane & 15;    // dim quad: dims [4l, 4l+4)
    const int row0 = (blockIdx.x * blockDim.x + threadIdx.x) >> 6;
    if (row0 >= N_NODES) return;
    const int row = __builtin_amdgcn_readfirstlane(row0);
    const size_t base = (size_t)row * D + (size_t)l * 4;

    // ---- round 1: ELL metadata + degree + out-RMW old value, all in flight
    const uint4 mA = *(const uint4*)(epad + (size_t)row * ELLW + g * 4);
    const uint4 mB = *(const uint4*)(epad + (size_t)row * ELLW + 16 + g * 4);
    const int  deg = degarr[row];
    f32x4 oldo = {0.f, 0.f, 0.f, 0.f};
    if (!first_head) oldo = *(const f32x4*)(out + base);

    float vA[4], vB[4];
    int   cA[4], cB[4];
    vA[0] = bf_lo(mA.x); cA[0] = (int)(mA.x >> 16);
    vA[1] = bf_lo(mA.y); cA[1] = (int)(mA.y >> 16);
    vA[2] = bf_lo(mA.z); cA[2] = (int)(mA.z >> 16);
    vA[3] = bf_lo(mA.w); cA[3] = (int)(mA.w >> 16);
    vB[0] = bf_lo(mB.x); cB[0] = (int)(mB.x >> 16);
    vB[1] = bf_lo(mB.y); cB[1] = (int)(mB.y >> 16);
    vB[2] = bf_lo(mB.z); cB[2] = (int)(mB.z >> 16);
    vB[3] = bf_lo(mB.w); cB[3] = (int)(mB.w >> 16);

    // ---- round 2: exec-masked gathers, all loads before any consumer
    uint2 rA[4], rB[4];
    #pragma unroll
    for (int u = 0; u < 4; ++u) rA[u] = make_uint2(0u, 0u);
    #pragma unroll
    for (int u = 0; u < 4; ++u) rB[u] = make_uint2(0u, 0u);
    #pragma unroll
    for (int u = 0; u < 4; ++u)
        if (vA[u] != 0.f)
            rA[u] = *(const uint2*)(tin + (size_t)cA[u] * D + l * 4);
    #pragma unroll
    for (int u = 0; u < 4; ++u)
        if (vB[u] != 0.f)
            rB[u] = *(const uint2*)(tin + (size_t)cB[u] * D + l * 4);

    float4 acc = {0.f, 0.f, 0.f, 0.f};
    #pragma unroll
    for (int u = 0; u < 4; ++u) {
        acc.x = fmaf(vA[u], bf_lo(rA[u].x), acc.x);
        acc.y = fmaf(vA[u], bf_hi(rA[u].x), acc.y);
        acc.z = fmaf(vA[u], bf_lo(rA[u].y), acc.z);
        acc.w = fmaf(vA[u], bf_hi(rA[u].y), acc.w);
    }
    #pragma unroll
    for (int u = 0; u < 4; ++u) {
        acc.x = fmaf(vB[u], bf_lo(rB[u].x), acc.x);
        acc.y = fmaf(vB[u], bf_hi(rB[u].x), acc.y);
        acc.z = fmaf(vB[u], bf_lo(rB[u].y), acc.z);
        acc.w = fmaf(vB[u], bf_hi(rB[u].y), acc.w);
    }

    // ---- rare CSR overflow (deg > 32), wave-uniform ----
    if (deg > ELLW) {
        const int e0 = row_ptr[row];
        const int e1 = e0 + deg;
        for (int e = e0 + ELLW; e < e1; e += 16) {
            #pragma unroll
            for (int u = 0; u < 4; ++u) {
                const int  ce = e + 4 * u + g;
                const bool ok = ce < e1;
                const int   c = ok ? edge_col[ce] : 0;
                const float v = ok ? bf_lo((uint_t)f2bf(edge_val[ce]) << 16) * 0.f + bf_lo(((uint_t)f2bf(edge_val[ce]))) : 0.f;
                // (match main-path bf16 val rounding)
                const float vv = ok ? bf_lo((uint_t)f2bf(edge_val[ce])) : 0.f;
                if (vv != 0.f) {
                    const uint2 r = *(const uint2*)(tin + (size_t)c * D + l * 4);
                    acc.x = fmaf(vv, bf_lo(r.x), acc.x);
                    acc.y = fmaf(vv, bf_hi(r.x), acc.y);
                    acc.z = fmaf(vv, bf_lo(r.y), acc.z);
                    acc.w = fmaf(vv, bf_hi(r.y), acc.w);
                }
                (void)v;
            }
        }
    }

    // ---- reduce across the 4 groups (lane bits 4,5) ----
    #pragma unroll
    for (int off = 16; off < 64; off <<= 1) {
        acc.x += __shfl_xor(acc.x, off, 64);
        acc.y += __shfl_xor(acc.y, off, 64);
        acc.z += __shfl_xor(acc.z, off, 64);
        acc.w += __shfl_xor(acc.w, off, 64);
    }

    if (g == 0) {
        f32x4 o = {acc.x + oldo.x, acc.y + oldo.y,
                   acc.z + oldo.z, acc.w + oldo.w};
        *(f32x4*)(out + base) = o;
        if (write_h) {
            uint2 hp;
            hp.x = (uint_t)f2bf(acc.x) | ((uint_t)f2bf(acc.y) << 16);
            hp.y = (uint_t)f2bf(acc.z) | ((uint_t)f2bf(acc.w) << 16);
            *(uint2*)(h + base) = hp;
        }
    }
}

// ---------------------------------------------------------------------------
extern "C" void kernel_launch(void* const* d_in, const int* in_sizes, int n_in,
                              void* d_out, int out_size, void* d_ws, size_t ws_size,
                              hipStream_t stream) {
    const float* x        = (const float*)d_in[0];  // [N, 64]
    const float* edge_val = (const float*)d_in[1];  // [E]
    const float* W        = (const float*)d_in[2];  // [4, 64, 64]
    const float* b        = (const float*)d_in[3];  // [4, 64]
    const int* edge_row   = (const int*)d_in[4];    // sorted
    const int* edge_col   = (const int*)d_in[5];
    const int* event_type = (const int*)d_in[6];    // [N] (int32 on device)
    float* out = (float*)d_out;

    // ws: epad uint32[N*32] | row_ptr[N+2] | degarr[N] | t bf16[N*64] | h bf16[N*64]
    char* p = (char*)d_ws;
    uint_t*   epad    = (uint_t*)p;                  p += (size_t)N_NODES * ELLW * 4;
    int*      row_ptr = (int*)p;                     p += (size_t)(N_NODES + 2) * 4;
    int*      degarr  = (int*)p;                     p += (size_t)N_NODES * 4;
    p = (char*)(((uintptr_t)p + 15) & ~(uintptr_t)15);
    ushort_t* t       = (ushort_t*)p;                p += (size_t)N_NODES * D * 2;
    ushort_t* h       = (ushort_t*)p;

    prep1_kernel<<<(N_NODES + 256) / 256, 256, 0, stream>>>(edge_row, row_ptr);
    prep2_kernel<<<(N_NODES * ELLW + 255) / 256, 256, 0, stream>>>(
        edge_col, edge_val, row_ptr, epad, degarr);

    const int sblk = (N_NODES * 64 + 255) / 256;   // one wave per row

    // head 0: linear(x fp32, masked) -> t ; spmm(t) -> h, out =
    linear_elu_kernel<0><<<1024, 256, 0, stream>>>(x, W, b, event_type, t);
    spmm_kernel<<<sblk, 256, 0, stream>>>(
        t, epad, degarr, row_ptr, edge_col, edge_val, h, out, 1, 1);

    // heads 1..3: linear(h bf16) -> t ; spmm(t) -> h, out +=
    for (int i = 1; i < N_HEAD; ++i) {
        linear_elu_kernel<1><<<1024, 256, 0, stream>>>(
            h, W + (size_t)i * D * D, b + (size_t)i * D, nullptr, t);
        spmm_kernel<<<sblk, 256, 0, stream>>>(
            t, epad, degarr, row_ptr, edge_col, edge_val, h, out, 0,
            (i < N_HEAD - 1) ? 1 : 0);
    }
}